// Round 1
// baseline (1851.891 us; speedup 1.0000x reference)
//
#include <hip/hip_runtime.h>
#include <hip/hip_bf16.h>

#define NDENSE 13
#define NSPARSE 26
#define NFEAT 39
#define EDIM 64
#define NLAYER 4
#define FFDIM 256
#define HIDN 256
#define VDN 50
#define VSN 50000
#define ATT_SCALE 0.35355339059327373f
#define LN_EPS 1e-5f

#define SBLK 4          // samples per block (kernel 1)
#define ROWS 160        // SBLK * 40 (39 tokens + 1 pad row per sample)
#define XST 72          // xb row stride in bf16 (144 B, 16B-aligned, 2-way banks)
#define QST 20          // q/k/v row stride in f32 (80 B, 16B-aligned)
#define MTILES 10       // 160 / 16
#define FFST 264        // ff scratch stride in bf16 (528 B)

typedef __bf16 bf16x8 __attribute__((ext_vector_type(8)));
typedef float f32x4 __attribute__((ext_vector_type(4)));

__device__ __forceinline__ f32x4 mfma16(bf16x8 a, bf16x8 b, f32x4 c) {
    return __builtin_amdgcn_mfma_f32_16x16x32_bf16(a, b, c, 0, 0, 0);
}

__device__ __forceinline__ float gelu_f(float x) {
    // jax.nn.gelu default: tanh approximation
    float u = 0.7978845608028654f * (x + 0.044715f * x * x * x);
    float e = __expf(2.0f * u);
    return x * (1.0f - 1.0f / (e + 1.0f));   // 0.5x(1+tanh(u))
}

// B fragment: rows k0 + g*8 + j (j=0..7), fixed col, from row-major W with leading dim ld.
__device__ __forceinline__ bf16x8 load_bfrag(const float* W, int ld, int k0, int col, int g) {
    bf16x8 b;
    #pragma unroll
    for (int j = 0; j < 8; ++j) b[j] = (__bf16)W[(k0 + g * 8 + j) * ld + col];
    return b;
}

// LayerNorm of one 16-row tile directly into K=64 A-fragments.
// Fragment layout: row = lane&15, k = (lane>>4)*8 + j  (frag0: k<32, frag1: k>=32)
__device__ __forceinline__ void ln_frag(const __bf16* xr, const float* gam, const float* bet,
                                        int g, bf16x8& a0, bf16x8& a1) {
    bf16x8 v0 = *(const bf16x8*)(xr + g * 8);
    bf16x8 v1 = *(const bf16x8*)(xr + 32 + g * 8);
    float x0[8], x1[8], s = 0.f, ss = 0.f;
    #pragma unroll
    for (int j = 0; j < 8; ++j) {
        x0[j] = (float)v0[j]; x1[j] = (float)v1[j];
        s += x0[j] + x1[j];
        ss += x0[j] * x0[j] + x1[j] * x1[j];
    }
    s += __shfl_xor(s, 16); ss += __shfl_xor(ss, 16);
    s += __shfl_xor(s, 32); ss += __shfl_xor(ss, 32);
    float mn = s * (1.0f / 64.0f);
    float rs = rsqrtf(ss * (1.0f / 64.0f) - mn * mn + LN_EPS);
    #pragma unroll
    for (int j = 0; j < 8; ++j) {
        int c0 = g * 8 + j, c1 = 32 + g * 8 + j;
        a0[j] = (__bf16)((x0[j] - mn) * rs * gam[c0] + bet[c0]);
        a1[j] = (__bf16)((x1[j] - mn) * rs * gam[c1] + bet[c1]);
    }
}

__global__ __launch_bounds__(256, 2)
void hstu_layers(const int* __restrict__ dfeat, const int* __restrict__ sfeat,
                 const float* __restrict__ demb, const float* __restrict__ semb,
                 const float* __restrict__ wq, const float* __restrict__ bq,
                 const float* __restrict__ wk, const float* __restrict__ bk,
                 const float* __restrict__ wv, const float* __restrict__ bv,
                 const float* __restrict__ wo, const float* __restrict__ bo,
                 const float* __restrict__ ln1g, const float* __restrict__ ln1b,
                 const float* __restrict__ ln2g, const float* __restrict__ ln2b,
                 const float* __restrict__ w1, const float* __restrict__ b1,
                 const float* __restrict__ w2, const float* __restrict__ b2,
                 __bf16* __restrict__ flatX)
{
    __shared__ __bf16 xb[ROWS * XST];        // 23040 B, x (residual stream), bf16
    __shared__ float qkv[3 * ROWS * QST];    // 38400 B, Q/K/V quarter buffers, f32

    float* qbuf = qkv;
    float* kbuf = qkv + ROWS * QST;
    float* vbuf = qkv + 2 * ROWS * QST;

    const int tid = threadIdx.x;
    const int lane = tid & 63, wave = tid >> 6;
    const int g = lane >> 4, r16 = lane & 15;
    const int s0 = blockIdx.x * SBLK;

    // ---------------- embedding gather ----------------
    for (int row = wave; row < ROWS; row += 4) {
        int sm = row / 40, f = row % 40;
        float val = 0.0f;
        if (f < NFEAT) {
            if (f < NDENSE) {
                int idx = dfeat[(s0 + sm) * NDENSE + f];
                val = demb[(f * VDN + idx) * EDIM + lane];
            } else {
                int idx = sfeat[(s0 + sm) * NSPARSE + (f - NDENSE)];
                val = semb[((long)(f - NDENSE) * VSN + idx) * EDIM + lane];
            }
        }
        xb[row * XST + lane] = (__bf16)val;
    }
    __syncthreads();

    for (int lay = 0; lay < NLAYER; ++lay) {
        const float* wq_l = wq + lay * EDIM * EDIM;
        const float* wk_l = wk + lay * EDIM * EDIM;
        const float* wv_l = wv + lay * EDIM * EDIM;
        const float* wo_l = wo + lay * EDIM * EDIM;
        const float* bq_l = bq + lay * EDIM;
        const float* bk_l = bk + lay * EDIM;
        const float* bv_l = bv + lay * EDIM;
        const float* bo_l = bo + lay * EDIM;
        const float* g1_l = ln1g + lay * EDIM;
        const float* be1_l = ln1b + lay * EDIM;
        const float* g2_l = ln2g + lay * EDIM;
        const float* be2_l = ln2b + lay * EDIM;
        const float* w1_l = w1 + lay * EDIM * FFDIM;
        const float* b1_l = b1 + lay * FFDIM;
        const float* w2_l = w2 + lay * FFDIM * EDIM;
        const float* b2_l = b2 + lay * EDIM;

        // O-proj accumulators: this wave owns output col strip n_o, all m-tiles.
        const int n_o = wave & 3;
        f32x4 acc_o[MTILES];
        {
            float bz = bo_l[n_o * 16 + r16];
            #pragma unroll
            for (int i = 0; i < MTILES; ++i) { f32x4 t = {bz, bz, bz, bz}; acc_o[i] = t; }
        }

        for (int qt = 0; qt < 4; ++qt) {   // quarter = 16 proj cols = 2 heads
            const int colq = qt * 16 + r16;

            // ---- A1: QKV projection for this quarter (MFMA, K=64) ----
            bf16x8 bfq0 = load_bfrag(wq_l, EDIM, 0, colq, g);
            bf16x8 bfq1 = load_bfrag(wq_l, EDIM, 32, colq, g);
            bf16x8 bfk0 = load_bfrag(wk_l, EDIM, 0, colq, g);
            bf16x8 bfk1 = load_bfrag(wk_l, EDIM, 32, colq, g);
            bf16x8 bfv0 = load_bfrag(wv_l, EDIM, 0, colq, g);
            bf16x8 bfv1 = load_bfrag(wv_l, EDIM, 32, colq, g);
            float biq = bq_l[colq], bik = bk_l[colq], biv = bv_l[colq];

            for (int mt = wave; mt < MTILES; mt += 4) {
                bf16x8 a0, a1;
                ln_frag(&xb[(mt * 16 + r16) * XST], g1_l, be1_l, g, a0, a1);
                f32x4 aq = {biq, biq, biq, biq};
                f32x4 ak = {bik, bik, bik, bik};
                f32x4 av = {biv, biv, biv, biv};
                aq = mfma16(a0, bfq0, aq); aq = mfma16(a1, bfq1, aq);
                ak = mfma16(a0, bfk0, ak); ak = mfma16(a1, bfk1, ak);
                av = mfma16(a0, bfv0, av); av = mfma16(a1, bfv1, av);
                #pragma unroll
                for (int r = 0; r < 4; ++r) {
                    int row = mt * 16 + g * 4 + r;
                    qbuf[row * QST + r16] = aq[r];
                    kbuf[row * QST + r16] = ak[r];
                    vbuf[row * QST + r16] = av[r];
                }
            }
            __syncthreads();

            // ---- A2: sigmoid attention, VALU, lane = q row ----
            for (int u = wave; u < SBLK * 2; u += 4) {
                int sm = u >> 1, d0 = (u & 1) * 8;
                int qq = lane < NFEAT ? lane : (NFEAT - 1);
                const float* Qr = &qbuf[(sm * 40 + qq) * QST + d0];
                f32x4 qv0 = *(const f32x4*)Qr;
                f32x4 qv1 = *(const f32x4*)(Qr + 4);
                f32x4 o0 = {0.f, 0.f, 0.f, 0.f}, o1 = {0.f, 0.f, 0.f, 0.f};
                for (int k = 0; k < NFEAT; ++k) {
                    const float* Kr = &kbuf[(sm * 40 + k) * QST + d0];   // broadcast
                    const float* Vr = &vbuf[(sm * 40 + k) * QST + d0];   // broadcast
                    f32x4 kv0 = *(const f32x4*)Kr, kv1 = *(const f32x4*)(Kr + 4);
                    f32x4 vv0 = *(const f32x4*)Vr, vv1 = *(const f32x4*)(Vr + 4);
                    float dot = qv0[0]*kv0[0] + qv0[1]*kv0[1] + qv0[2]*kv0[2] + qv0[3]*kv0[3]
                              + qv1[0]*kv1[0] + qv1[1]*kv1[1] + qv1[2]*kv1[2] + qv1[3]*kv1[3];
                    float sg = 1.0f / (1.0f + __expf(-dot * ATT_SCALE));
                    o0 += vv0 * sg;
                    o1 += vv1 * sg;
                }
                if (lane < NFEAT) {      // o overwrites Q in place (same col strip)
                    float* Or = &qbuf[(sm * 40 + lane) * QST + d0];
                    *(f32x4*)Or = o0;
                    *(f32x4*)(Or + 4) = o1;
                }
            }
            __syncthreads();

            // ---- A3: O-proj partial for this quarter (K=16 zero-padded to 32) ----
            bf16x8 bfo;
            #pragma unroll
            for (int j = 0; j < 8; ++j) {
                int k = g * 8 + j;
                bfo[j] = (k < 16) ? (__bf16)wo_l[(qt * 16 + k) * EDIM + n_o * 16 + r16]
                                  : (__bf16)0.0f;
            }
            #pragma unroll
            for (int mt = 0; mt < MTILES; ++mt) {
                const float* orow = &qbuf[(mt * 16 + r16) * QST + g * 8];
                bf16x8 af;
                #pragma unroll
                for (int j = 0; j < 8; ++j) af[j] = (g < 2) ? (__bf16)orow[j] : (__bf16)0.0f;
                acc_o[mt] = mfma16(af, bfo, acc_o[mt]);
            }
            __syncthreads();   // next quarter overwrites q/k/v buffers
        }

        // ---- A4: residual add of O-projection ----
        #pragma unroll
        for (int mt = 0; mt < MTILES; ++mt) {
            #pragma unroll
            for (int r = 0; r < 4; ++r) {
                int row = mt * 16 + g * 4 + r, col = n_o * 16 + r16;
                xb[row * XST + col] = (__bf16)((float)xb[row * XST + col] + acc_o[mt][r]);
            }
        }
        __syncthreads();

        // ---- B: MLP (per m-tile, ff round-trip through per-wave LDS scratch) ----
        __bf16* ffs = ((__bf16*)qkv) + wave * (16 * FFST);   // 8448 B per wave, aliases q/k/v
        for (int mt = wave; mt < MTILES; mt += 4) {
            bf16x8 a0, a1;
            ln_frag(&xb[(mt * 16 + r16) * XST], g2_l, be2_l, g, a0, a1);
            for (int n = 0; n < 16; ++n) {
                float bz = b1_l[n * 16 + r16];
                f32x4 acc = {bz, bz, bz, bz};
                acc = mfma16(a0, load_bfrag(w1_l, FFDIM, 0, n * 16 + r16, g), acc);
                acc = mfma16(a1, load_bfrag(w1_l, FFDIM, 32, n * 16 + r16, g), acc);
                #pragma unroll
                for (int r = 0; r < 4; ++r)
                    ffs[(g * 4 + r) * FFST + n * 16 + r16] = (__bf16)gelu_f(acc[r]);
            }
            #pragma unroll
            for (int n2 = 0; n2 < 4; ++n2) {
                float bz = b2_l[n2 * 16 + r16];
                f32x4 acc = {bz, bz, bz, bz};
                #pragma unroll
                for (int kf = 0; kf < 8; ++kf) {
                    bf16x8 af = *(const bf16x8*)&ffs[r16 * FFST + kf * 32 + g * 8];
                    acc = mfma16(af, load_bfrag(w2_l, EDIM, kf * 32, n2 * 16 + r16, g), acc);
                }
                #pragma unroll
                for (int r = 0; r < 4; ++r) {
                    int row = mt * 16 + g * 4 + r, col = n2 * 16 + r16;
                    xb[row * XST + col] = (__bf16)((float)xb[row * XST + col] + acc[r]);
                }
            }
        }
        __syncthreads();
    }

    // ---------------- write flat activations (bf16) ----------------
    for (int row = wave; row < ROWS; row += 4) {
        int sm = row / 40, f = row % 40;
        if (f < NFEAT)
            flatX[((long)(s0 + sm) * NFEAT + f) * EDIM + lane] = xb[row * XST + lane];
    }
}

__global__ __launch_bounds__(512)
void final_mlp(const __bf16* __restrict__ flatX, const float* __restrict__ ow1,
               const float* __restrict__ ob1, const float* __restrict__ ow2,
               const float* __restrict__ ob2, float* __restrict__ out)
{
    __shared__ __bf16 hbuf[32 * FFST];   // 16896 B
    const int tid = threadIdx.x, lane = tid & 63, wave = tid >> 6;
    const int g = lane >> 4, r16 = lane & 15;
    const int m = wave & 1;              // m-tile 0/1 (16 samples each)
    const long base = (long)blockIdx.x * 32;
    const long arow = (base + m * 16 + r16) * (long)(NFEAT * EDIM);

    f32x4 acc[4];
    #pragma unroll
    for (int i = 0; i < 4; ++i) {
        int n = (wave >> 1) + i * 4;
        float bz = ob1[n * 16 + r16];
        f32x4 t = {bz, bz, bz, bz};
        acc[i] = t;
    }
    for (int kf = 0; kf < 78; ++kf) {    // K = 2496
        bf16x8 af = *(const bf16x8*)&flatX[arow + kf * 32 + g * 8];
        #pragma unroll
        for (int i = 0; i < 4; ++i) {
            int n = (wave >> 1) + i * 4;
            bf16x8 bfr;
            #pragma unroll
            for (int j = 0; j < 8; ++j)
                bfr[j] = (__bf16)ow1[(kf * 32 + g * 8 + j) * HIDN + n * 16 + r16];
            acc[i] = mfma16(af, bfr, acc[i]);
        }
    }
    #pragma unroll
    for (int i = 0; i < 4; ++i) {
        int n = (wave >> 1) + i * 4;
        #pragma unroll
        for (int r = 0; r < 4; ++r) {
            float h = acc[i][r];
            hbuf[(m * 16 + g * 4 + r) * FFST + n * 16 + r16] = (__bf16)(h > 0.f ? h : 0.f);
        }
    }
    __syncthreads();
    #pragma unroll
    for (int i = 0; i < 4; ++i) {
        int sm = wave * 4 + i;
        float part = (float)hbuf[sm * FFST + lane]       * ow2[lane]
                   + (float)hbuf[sm * FFST + 64 + lane]  * ow2[64 + lane]
                   + (float)hbuf[sm * FFST + 128 + lane] * ow2[128 + lane]
                   + (float)hbuf[sm * FFST + 192 + lane] * ow2[192 + lane];
        #pragma unroll
        for (int off = 32; off >= 1; off >>= 1) part += __shfl_xor(part, off);
        if (lane == 0) out[base + sm] = 1.0f / (1.0f + __expf(-(part + ob2[0])));
    }
}

extern "C" void kernel_launch(void* const* d_in, const int* in_sizes, int n_in,
                              void* d_out, int out_size, void* d_ws, size_t ws_size,
                              hipStream_t stream)
{
    const int*   dfeat = (const int*)d_in[0];
    const int*   sfeat = (const int*)d_in[1];
    const float* demb  = (const float*)d_in[2];
    const float* semb  = (const float*)d_in[3];
    const float* wq    = (const float*)d_in[4];
    const float* bq    = (const float*)d_in[5];
    const float* wk    = (const float*)d_in[6];
    const float* bk    = (const float*)d_in[7];
    const float* wv    = (const float*)d_in[8];
    const float* bv    = (const float*)d_in[9];
    const float* wo    = (const float*)d_in[10];
    const float* bo    = (const float*)d_in[11];
    const float* ln1g  = (const float*)d_in[12];
    const float* ln1b  = (const float*)d_in[13];
    const float* ln2g  = (const float*)d_in[14];
    const float* ln2b  = (const float*)d_in[15];
    const float* w1    = (const float*)d_in[16];
    const float* b1    = (const float*)d_in[17];
    const float* w2    = (const float*)d_in[18];
    const float* b2    = (const float*)d_in[19];
    const float* ow1   = (const float*)d_in[20];
    const float* ob1   = (const float*)d_in[21];
    const float* ow2   = (const float*)d_in[22];
    const float* ob2   = (const float*)d_in[23];

    __bf16* flatX = (__bf16*)d_ws;    // 8192*2496*2 = ~40.9 MB
    float* out = (float*)d_out;

    hstu_layers<<<8192 / SBLK, 256, 0, stream>>>(dfeat, sfeat, demb, semb,
        wq, bq, wk, bk, wv, bv, wo, bo, ln1g, ln1b, ln2g, ln2b,
        w1, b1, w2, b2, flatX);
    final_mlp<<<8192 / 32, 512, 0, stream>>>(flatX, ow1, ob1, ow2, ob2, out);
}

// Round 4
// 1340.935 us; speedup vs baseline: 1.3810x; 1.3810x over previous
//
#include <hip/hip_runtime.h>
#include <hip/hip_bf16.h>

#define NDENSE 13
#define NSPARSE 26
#define NFEAT 39
#define EDIM 64
#define NLAYER 4
#define FFDIM 256
#define HIDN 256
#define VDN 50
#define VSN 50000
#define ATT_SCALE 0.35355339059327373f
#define LN_EPS 1e-5f

#define SBLK 4          // samples per block (kernel 1)
#define ROWS 160        // SBLK * 40 (39 tokens + 1 pad row per sample)
#define XST 72          // xb row stride in bf16 (144 B, 16B-aligned)
#define QST 20          // q/k/v row stride in f32 (80 B, 16B-aligned)
#define MTILES 10       // 160 / 16
#define FFST 264        // ff scratch stride in bf16 (528 B)

// ---- packed (transposed, bf16) weights in d_ws after flatX ----
#define FLATX_ELEMS (8192L * NFEAT * EDIM)   // 20,447,232 bf16
#define PK_WKT 4096           // wqT:  [64][64]
#define PK_WVT 8192
#define PK_WOT 12288
#define PK_W1T 16384          // w1T:  [256][64]
#define PK_W2T 32768          // w2T:  [64][256]
#define PK_LAYER 49152        // 4*4096 + 16384 + 16384
#define PK_OW1T 196608        // = 4*PK_LAYER; ow1T: [256][2496]
#define PK_TOTAL 835584       // 196608 + 256*2496

typedef __bf16 bf16x8 __attribute__((ext_vector_type(8)));
typedef float f32x4 __attribute__((ext_vector_type(4)));

__device__ __forceinline__ f32x4 mfma16(bf16x8 a, bf16x8 b, f32x4 c) {
    return __builtin_amdgcn_mfma_f32_16x16x32_bf16(a, b, c, 0, 0, 0);
}

__device__ __forceinline__ float sigmoid_f(float x) {
    return __builtin_amdgcn_rcpf(1.0f + __expf(-x));
}

__device__ __forceinline__ float gelu_f(float x) {
    // x * sigmoid(2u), u = 0.7978845608*(x + 0.044715 x^3)  (tanh-approx gelu)
    float u2 = 1.5957691216057308f * x + 0.07135481627159659f * x * x * x;
    return x * sigmoid_f(u2);
}

// B fragment from packed transposed weights: WT[col][k], k = k0..k0+7 contiguous.
__device__ __forceinline__ bf16x8 ldfrag(const __bf16* WT, int ld, int col, int k0) {
    return *(const bf16x8*)&WT[col * ld + k0];
}

// LayerNorm of one 16-row tile directly into K=64 A-fragments.
// Fragment layout: row = lane&15, k = (lane>>4)*8 + j
__device__ __forceinline__ void ln_frag(const __bf16* xr, const float* gam, const float* bet,
                                        int g, bf16x8& a0, bf16x8& a1) {
    bf16x8 v0 = *(const bf16x8*)(xr + g * 8);
    bf16x8 v1 = *(const bf16x8*)(xr + 32 + g * 8);
    float x0[8], x1[8], s = 0.f, ss = 0.f;
    #pragma unroll
    for (int j = 0; j < 8; ++j) {
        x0[j] = (float)v0[j]; x1[j] = (float)v1[j];
        s += x0[j] + x1[j];
        ss += x0[j] * x0[j] + x1[j] * x1[j];
    }
    s += __shfl_xor(s, 16); ss += __shfl_xor(ss, 16);
    s += __shfl_xor(s, 32); ss += __shfl_xor(ss, 32);
    float mn = s * (1.0f / 64.0f);
    float rs = rsqrtf(ss * (1.0f / 64.0f) - mn * mn + LN_EPS);
    float gv0[8], gv1[8], bv0[8], bv1[8];
    *(f32x4*)&gv0[0] = *(const f32x4*)&gam[g * 8];
    *(f32x4*)&gv0[4] = *(const f32x4*)&gam[g * 8 + 4];
    *(f32x4*)&gv1[0] = *(const f32x4*)&gam[32 + g * 8];
    *(f32x4*)&gv1[4] = *(const f32x4*)&gam[32 + g * 8 + 4];
    *(f32x4*)&bv0[0] = *(const f32x4*)&bet[g * 8];
    *(f32x4*)&bv0[4] = *(const f32x4*)&bet[g * 8 + 4];
    *(f32x4*)&bv1[0] = *(const f32x4*)&bet[32 + g * 8];
    *(f32x4*)&bv1[4] = *(const f32x4*)&bet[32 + g * 8 + 4];
    #pragma unroll
    for (int j = 0; j < 8; ++j) {
        a0[j] = (__bf16)((x0[j] - mn) * rs * gv0[j] + bv0[j]);
        a1[j] = (__bf16)((x1[j] - mn) * rs * gv1[j] + bv1[j]);
    }
}

// ---------------- weight pack: transpose + bf16 ----------------
__global__ __launch_bounds__(256)
void pack_weights(const float* __restrict__ wq, const float* __restrict__ wk,
                  const float* __restrict__ wv, const float* __restrict__ wo,
                  const float* __restrict__ w1, const float* __restrict__ w2,
                  const float* __restrict__ ow1, __bf16* __restrict__ pk)
{
    int idx = blockIdx.x * 256 + threadIdx.x;
    if (idx >= PK_TOTAL) return;
    float v;
    if (idx < PK_OW1T) {
        int l = idx / PK_LAYER, r = idx - l * PK_LAYER;
        const float* src; int sh, N, off;
        if (r < PK_WKT)      { src = wq + l * 4096;  sh = 6; N = 64;  off = r; }
        else if (r < PK_WVT) { src = wk + l * 4096;  sh = 6; N = 64;  off = r - PK_WKT; }
        else if (r < PK_WOT) { src = wv + l * 4096;  sh = 6; N = 64;  off = r - PK_WVT; }
        else if (r < PK_W1T) { src = wo + l * 4096;  sh = 6; N = 64;  off = r - PK_WOT; }
        else if (r < PK_W2T) { src = w1 + l * 16384; sh = 6; N = 256; off = r - PK_W1T; }
        else                 { src = w2 + l * 16384; sh = 8; N = 64;  off = r - PK_W2T; }
        int col = off >> sh, k = off & ((1 << sh) - 1);
        v = src[k * N + col];
    } else {
        int off = idx - PK_OW1T;
        int col = off / 2496, k = off - col * 2496;
        v = ow1[k * 256 + col];
    }
    pk[idx] = (__bf16)v;
}

__global__ __launch_bounds__(256, 2)
void hstu_layers(const int* __restrict__ dfeat, const int* __restrict__ sfeat,
                 const float* __restrict__ demb, const float* __restrict__ semb,
                 const float* __restrict__ bq, const float* __restrict__ bk,
                 const float* __restrict__ bv, const float* __restrict__ bo,
                 const float* __restrict__ ln1g, const float* __restrict__ ln1b,
                 const float* __restrict__ ln2g, const float* __restrict__ ln2b,
                 const float* __restrict__ b1, const float* __restrict__ b2,
                 const __bf16* __restrict__ pk, __bf16* __restrict__ flatX)
{
    __shared__ __bf16 xb[ROWS * XST];        // 23040 B, residual stream
    __shared__ float qkv[3 * ROWS * QST];    // 38400 B, Q/K/V quarter buffers

    float* qbuf = qkv;
    float* kbuf = qkv + ROWS * QST;
    float* vbuf = qkv + 2 * ROWS * QST;

    const int tid = threadIdx.x;
    const int lane = tid & 63, wave = tid >> 6;
    const int g = lane >> 4, r16 = lane & 15;
    const int s0 = blockIdx.x * SBLK;

    // ---------------- embedding gather ----------------
    for (int row = wave; row < ROWS; row += 4) {
        int sm = row / 40, f = row % 40;
        float val = 0.0f;
        if (f < NFEAT) {
            if (f < NDENSE) {
                int idx = dfeat[(s0 + sm) * NDENSE + f];
                val = demb[(f * VDN + idx) * EDIM + lane];
            } else {
                int idx = sfeat[(s0 + sm) * NSPARSE + (f - NDENSE)];
                val = semb[((long)(f - NDENSE) * VSN + idx) * EDIM + lane];
            }
        }
        xb[row * XST + lane] = (__bf16)val;
    }
    __syncthreads();

    for (int lay = 0; lay < NLAYER; ++lay) {
        const __bf16* wqT = pk + lay * PK_LAYER;
        const __bf16* wkT = wqT + PK_WKT;
        const __bf16* wvT = wqT + PK_WVT;
        const __bf16* woT = wqT + PK_WOT;
        const __bf16* w1T = wqT + PK_W1T;
        const __bf16* w2T = wqT + PK_W2T;
        const float* bq_l = bq + lay * EDIM;
        const float* bk_l = bk + lay * EDIM;
        const float* bv_l = bv + lay * EDIM;
        const float* bo_l = bo + lay * EDIM;
        const float* g1_l = ln1g + lay * EDIM;
        const float* be1_l = ln1b + lay * EDIM;
        const float* g2_l = ln2g + lay * EDIM;
        const float* be2_l = ln2b + lay * EDIM;
        const float* b1_l = b1 + lay * FFDIM;
        const float* b2_l = b2 + lay * EDIM;

        // O-proj accumulators: this wave owns col strip n_o, all m-tiles.
        const int n_o = wave & 3;
        f32x4 acc_o[MTILES];
        {
            float bz = bo_l[n_o * 16 + r16];
            #pragma unroll
            for (int i = 0; i < MTILES; ++i) { f32x4 t = {bz, bz, bz, bz}; acc_o[i] = t; }
        }

        for (int qt = 0; qt < 4; ++qt) {   // quarter = 16 proj cols = 2 heads
            const int colq = qt * 16 + r16;

            // ---- A1: QKV projection for this quarter (MFMA, K=64) ----
            bf16x8 bfq0 = ldfrag(wqT, EDIM, colq, g * 8);
            bf16x8 bfq1 = ldfrag(wqT, EDIM, colq, 32 + g * 8);
            bf16x8 bfk0 = ldfrag(wkT, EDIM, colq, g * 8);
            bf16x8 bfk1 = ldfrag(wkT, EDIM, colq, 32 + g * 8);
            bf16x8 bfv0 = ldfrag(wvT, EDIM, colq, g * 8);
            bf16x8 bfv1 = ldfrag(wvT, EDIM, colq, 32 + g * 8);
            float biq = bq_l[colq], bik = bk_l[colq], biv = bv_l[colq];

            for (int mt = wave; mt < MTILES; mt += 4) {
                bf16x8 a0, a1;
                ln_frag(&xb[(mt * 16 + r16) * XST], g1_l, be1_l, g, a0, a1);
                f32x4 aq = {biq, biq, biq, biq};
                f32x4 ak = {bik, bik, bik, bik};
                f32x4 av = {biv, biv, biv, biv};
                aq = mfma16(a0, bfq0, aq); aq = mfma16(a1, bfq1, aq);
                ak = mfma16(a0, bfk0, ak); ak = mfma16(a1, bfk1, ak);
                av = mfma16(a0, bfv0, av); av = mfma16(a1, bfv1, av);
                #pragma unroll
                for (int r = 0; r < 4; ++r) {
                    int row = mt * 16 + g * 4 + r;
                    qbuf[row * QST + r16] = aq[r];
                    kbuf[row * QST + r16] = ak[r];
                    vbuf[row * QST + r16] = av[r];
                }
            }
            __syncthreads();

            // ---- A2: sigmoid attention, VALU, lane = q row ----
            for (int u = wave; u < SBLK * 2; u += 4) {
                int sm = u >> 1, d0 = (u & 1) * 8;
                int qq = lane < NFEAT ? lane : (NFEAT - 1);
                const float* Qr = &qbuf[(sm * 40 + qq) * QST + d0];
                f32x4 qv0 = *(const f32x4*)Qr;
                f32x4 qv1 = *(const f32x4*)(Qr + 4);
                f32x4 o0 = {0.f, 0.f, 0.f, 0.f}, o1 = {0.f, 0.f, 0.f, 0.f};
                for (int k = 0; k < NFEAT; ++k) {
                    const float* Kr = &kbuf[(sm * 40 + k) * QST + d0];   // broadcast
                    const float* Vr = &vbuf[(sm * 40 + k) * QST + d0];   // broadcast
                    f32x4 kv0 = *(const f32x4*)Kr, kv1 = *(const f32x4*)(Kr + 4);
                    f32x4 vv0 = *(const f32x4*)Vr, vv1 = *(const f32x4*)(Vr + 4);
                    float dot = qv0[0]*kv0[0] + qv0[1]*kv0[1] + qv0[2]*kv0[2] + qv0[3]*kv0[3]
                              + qv1[0]*kv1[0] + qv1[1]*kv1[1] + qv1[2]*kv1[2] + qv1[3]*kv1[3];
                    float sg = sigmoid_f(dot * ATT_SCALE);
                    o0 += vv0 * sg;
                    o1 += vv1 * sg;
                }
                if (lane < NFEAT) {      // o overwrites Q in place
                    float* Or = &qbuf[(sm * 40 + lane) * QST + d0];
                    *(f32x4*)Or = o0;
                    *(f32x4*)(Or + 4) = o1;
                }
            }
            __syncthreads();

            // ---- A3: O-proj partial for this quarter (K=16 zero-padded to 32) ----
            bf16x8 bfo;
            if (g < 2) {
                bfo = ldfrag(woT, EDIM, n_o * 16 + r16, qt * 16 + g * 8);
            } else {
                #pragma unroll
                for (int j = 0; j < 8; ++j) bfo[j] = (__bf16)0.0f;
            }
            #pragma unroll
            for (int mt = 0; mt < MTILES; ++mt) {
                bf16x8 af;
                if (g < 2) {
                    const float* orow = &qbuf[(mt * 16 + r16) * QST + g * 8];
                    f32x4 q0 = *(const f32x4*)orow;
                    f32x4 q1 = *(const f32x4*)(orow + 4);
                    #pragma unroll
                    for (int j = 0; j < 4; ++j) { af[j] = (__bf16)q0[j]; af[4 + j] = (__bf16)q1[j]; }
                } else {
                    #pragma unroll
                    for (int j = 0; j < 8; ++j) af[j] = (__bf16)0.0f;
                }
                acc_o[mt] = mfma16(af, bfo, acc_o[mt]);
            }
            __syncthreads();   // next quarter overwrites q/k/v buffers
        }

        // ---- A4: residual add of O-projection ----
        #pragma unroll
        for (int mt = 0; mt < MTILES; ++mt) {
            #pragma unroll
            for (int r = 0; r < 4; ++r) {
                int row = mt * 16 + g * 4 + r, col = n_o * 16 + r16;
                xb[row * XST + col] = (__bf16)((float)xb[row * XST + col] + acc_o[mt][r]);
            }
        }
        __syncthreads();

        // ---- B: MLP (per m-tile, ff round-trip through per-wave LDS scratch) ----
        __bf16* ffs = ((__bf16*)qkv) + wave * (16 * FFST);   // 8448 B per wave
        for (int mt = wave; mt < MTILES; mt += 4) {
            bf16x8 a0, a1;
            ln_frag(&xb[(mt * 16 + r16) * XST], g2_l, be2_l, g, a0, a1);
            for (int n = 0; n < 16; ++n) {
                float bz = b1_l[n * 16 + r16];
                f32x4 acc = {bz, bz, bz, bz};
                acc = mfma16(a0, ldfrag(w1T, EDIM, n * 16 + r16, g * 8), acc);
                acc = mfma16(a1, ldfrag(w1T, EDIM, n * 16 + r16, 32 + g * 8), acc);
                #pragma unroll
                for (int r = 0; r < 4; ++r)
                    ffs[(g * 4 + r) * FFST + n * 16 + r16] = (__bf16)gelu_f(acc[r]);
            }
            #pragma unroll
            for (int n2 = 0; n2 < 4; ++n2) {
                float bz = b2_l[n2 * 16 + r16];
                f32x4 acc = {bz, bz, bz, bz};
                #pragma unroll
                for (int kf = 0; kf < 8; ++kf) {
                    bf16x8 af = *(const bf16x8*)&ffs[r16 * FFST + kf * 32 + g * 8];
                    acc = mfma16(af, ldfrag(w2T, FFDIM, n2 * 16 + r16, kf * 32 + g * 8), acc);
                }
                #pragma unroll
                for (int r = 0; r < 4; ++r) {
                    int row = mt * 16 + g * 4 + r, col = n2 * 16 + r16;
                    xb[row * XST + col] = (__bf16)((float)xb[row * XST + col] + acc[r]);
                }
            }
        }
        __syncthreads();
    }

    // ---------------- write flat activations (bf16) ----------------
    for (int row = wave; row < ROWS; row += 4) {
        int sm = row / 40, f = row % 40;
        if (f < NFEAT)
            flatX[((long)(s0 + sm) * NFEAT + f) * EDIM + lane] = xb[row * XST + lane];
    }
}

__global__ __launch_bounds__(512)
void final_mlp(const __bf16* __restrict__ flatX, const __bf16* __restrict__ ow1T,
               const float* __restrict__ ob1, const float* __restrict__ ow2,
               const float* __restrict__ ob2, float* __restrict__ out)
{
    __shared__ __bf16 hbuf[32 * FFST];   // 16896 B
    const int tid = threadIdx.x, lane = tid & 63, wave = tid >> 6;
    const int g = lane >> 4, r16 = lane & 15;
    const int m = wave & 1;              // m-tile 0/1 (16 samples each)
    const long base = (long)blockIdx.x * 32;
    const long arow = (base + m * 16 + r16) * (long)(NFEAT * EDIM);

    f32x4 acc[4];
    #pragma unroll
    for (int i = 0; i < 4; ++i) {
        int n = (wave >> 1) + i * 4;
        float bz = ob1[n * 16 + r16];
        f32x4 t = {bz, bz, bz, bz};
        acc[i] = t;
    }
    for (int kf = 0; kf < 78; ++kf) {    // K = 2496
        bf16x8 af = *(const bf16x8*)&flatX[arow + kf * 32 + g * 8];
        #pragma unroll
        for (int i = 0; i < 4; ++i) {
            int n = (wave >> 1) + i * 4;
            bf16x8 bfr = ldfrag(ow1T, NFEAT * EDIM, n * 16 + r16, kf * 32 + g * 8);
            acc[i] = mfma16(af, bfr, acc[i]);
        }
    }
    #pragma unroll
    for (int i = 0; i < 4; ++i) {
        int n = (wave >> 1) + i * 4;
        #pragma unroll
        for (int r = 0; r < 4; ++r) {
            float h = acc[i][r];
            hbuf[(m * 16 + g * 4 + r) * FFST + n * 16 + r16] = (__bf16)(h > 0.f ? h : 0.f);
        }
    }
    __syncthreads();
    float w2v0 = ow2[lane], w2v1 = ow2[64 + lane], w2v2 = ow2[128 + lane], w2v3 = ow2[192 + lane];
    float bias2 = ob2[0];
    #pragma unroll
    for (int i = 0; i < 4; ++i) {
        int sm = wave * 4 + i;
        float part = (float)hbuf[sm * FFST + lane]       * w2v0
                   + (float)hbuf[sm * FFST + 64 + lane]  * w2v1
                   + (float)hbuf[sm * FFST + 128 + lane] * w2v2
                   + (float)hbuf[sm * FFST + 192 + lane] * w2v3;
        #pragma unroll
        for (int off = 32; off >= 1; off >>= 1) part += __shfl_xor(part, off);
        if (lane == 0) out[base + sm] = sigmoid_f(part + bias2);
    }
}

extern "C" void kernel_launch(void* const* d_in, const int* in_sizes, int n_in,
                              void* d_out, int out_size, void* d_ws, size_t ws_size,
                              hipStream_t stream)
{
    const int*   dfeat = (const int*)d_in[0];
    const int*   sfeat = (const int*)d_in[1];
    const float* demb  = (const float*)d_in[2];
    const float* semb  = (const float*)d_in[3];
    const float* wq    = (const float*)d_in[4];
    const float* bq    = (const float*)d_in[5];
    const float* wk    = (const float*)d_in[6];
    const float* bk    = (const float*)d_in[7];
    const float* wv    = (const float*)d_in[8];
    const float* bv    = (const float*)d_in[9];
    const float* wo    = (const float*)d_in[10];
    const float* bo    = (const float*)d_in[11];
    const float* ln1g  = (const float*)d_in[12];
    const float* ln1b  = (const float*)d_in[13];
    const float* ln2g  = (const float*)d_in[14];
    const float* ln2b  = (const float*)d_in[15];
    const float* w1    = (const float*)d_in[16];
    const float* b1    = (const float*)d_in[17];
    const float* w2    = (const float*)d_in[18];
    const float* b2    = (const float*)d_in[19];
    const float* ow1   = (const float*)d_in[20];
    const float* ob1   = (const float*)d_in[21];
    const float* ow2   = (const float*)d_in[22];
    const float* ob2   = (const float*)d_in[23];

    __bf16* flatX = (__bf16*)d_ws;                 // 40.9 MB
    __bf16* pk    = ((__bf16*)d_ws) + FLATX_ELEMS; // +1.7 MB packed weights
    float* out = (float*)d_out;

    pack_weights<<<(PK_TOTAL + 255) / 256, 256, 0, stream>>>(wq, wk, wv, wo, w1, w2, ow1, pk);
    hstu_layers<<<8192 / SBLK, 256, 0, stream>>>(dfeat, sfeat, demb, semb,
        bq, bk, bv, bo, ln1g, ln1b, ln2g, ln2b, b1, b2, pk, flatX);
    final_mlp<<<8192 / 32, 512, 0, stream>>>(flatX, pk + PK_OW1T, ob1, ow2, ob2, out);
}

// Round 5
// 1282.517 us; speedup vs baseline: 1.4439x; 1.0455x over previous
//
#include <hip/hip_runtime.h>
#include <hip/hip_bf16.h>

#define NDENSE 13
#define NSPARSE 26
#define NFEAT 39
#define EDIM 64
#define NLAYER 4
#define FFDIM 256
#define HIDN 256
#define VDN 50
#define VSN 50000
#define NSAMP 8192
#define LN_EPS 1e-5f

// Q pre-scale: HD^-0.5 * log2(e), so sigmoid = rcp(1 + exp2(-dot))
#define QSCL 0.5100697f
// gelu: x * sigmoid2(C1*x + C2*x^3), constants pre-multiplied by log2(e)
#define GC1 2.3022082f
#define GC2 0.10294324f

#define SBLK 3          // samples per block
#define SROWS 120       // real rows (3 * 40)
#define ROWS 128        // padded to 8 m-tiles
#define XST 72          // xb row stride in bf16 (144 B, 16B-aligned)
#define QST 20          // q/k/v row stride in f32 (80 B, 16B-aligned)
#define MTILES 8        // 128 / 16 -> 2 per wave, balanced
#define FST2 136        // ff scratch stride in bf16 (272 B), 128 cols + pad

// ---- packed (transposed, bf16) weights in d_ws after flatX ----
#define FLATX_ELEMS (8192L * NFEAT * EDIM)   // 20,447,232 bf16
#define PK_WKT 4096           // wqT:  [64][64]
#define PK_WVT 8192
#define PK_WOT 12288
#define PK_W1T 16384          // w1T:  [256][64]
#define PK_W2T 32768          // w2T:  [64][256]
#define PK_LAYER 49152
#define PK_OW1T 196608        // ow1T: [256][2496]
#define PK_TOTAL 835584

typedef __bf16 bf16x8 __attribute__((ext_vector_type(8)));
typedef float f32x4 __attribute__((ext_vector_type(4)));

__device__ __forceinline__ f32x4 mfma16(bf16x8 a, bf16x8 b, f32x4 c) {
    return __builtin_amdgcn_mfma_f32_16x16x32_bf16(a, b, c, 0, 0, 0);
}

__device__ __forceinline__ float exp2_fast(float x) {
#if __has_builtin(__builtin_amdgcn_exp2f)
    return __builtin_amdgcn_exp2f(x);
#else
    return exp2f(x);
#endif
}

// x already scaled by log2(e)
__device__ __forceinline__ float sigmoid2(float x) {
    return __builtin_amdgcn_rcpf(1.0f + exp2_fast(-x));
}

__device__ __forceinline__ float gelu_f(float x) {
    return x * sigmoid2(GC1 * x + GC2 * x * x * x);
}

// B fragment from packed transposed weights: WT[col][k], k = k0..k0+7 contiguous.
__device__ __forceinline__ bf16x8 ldfrag(const __bf16* WT, int ld, int col, int k0) {
    return *(const bf16x8*)&WT[col * ld + k0];
}

// LayerNorm of one 16-row tile directly into K=64 A-fragments.
// Fragment layout: row = lane&15, k = (lane>>4)*8 + j
__device__ __forceinline__ void ln_frag(const __bf16* xr, const float* gam, const float* bet,
                                        int g, bf16x8& a0, bf16x8& a1) {
    bf16x8 v0 = *(const bf16x8*)(xr + g * 8);
    bf16x8 v1 = *(const bf16x8*)(xr + 32 + g * 8);
    float x0[8], x1[8], s = 0.f, ss = 0.f;
    #pragma unroll
    for (int j = 0; j < 8; ++j) {
        x0[j] = (float)v0[j]; x1[j] = (float)v1[j];
        s += x0[j] + x1[j];
        ss += x0[j] * x0[j] + x1[j] * x1[j];
    }
    s += __shfl_xor(s, 16); ss += __shfl_xor(ss, 16);
    s += __shfl_xor(s, 32); ss += __shfl_xor(ss, 32);
    float mn = s * (1.0f / 64.0f);
    float rs = rsqrtf(ss * (1.0f / 64.0f) - mn * mn + LN_EPS);
    float gv0[8], gv1[8], bv0[8], bv1[8];
    *(f32x4*)&gv0[0] = *(const f32x4*)&gam[g * 8];
    *(f32x4*)&gv0[4] = *(const f32x4*)&gam[g * 8 + 4];
    *(f32x4*)&gv1[0] = *(const f32x4*)&gam[32 + g * 8];
    *(f32x4*)&gv1[4] = *(const f32x4*)&gam[32 + g * 8 + 4];
    *(f32x4*)&bv0[0] = *(const f32x4*)&bet[g * 8];
    *(f32x4*)&bv0[4] = *(const f32x4*)&bet[g * 8 + 4];
    *(f32x4*)&bv1[0] = *(const f32x4*)&bet[32 + g * 8];
    *(f32x4*)&bv1[4] = *(const f32x4*)&bet[32 + g * 8 + 4];
    #pragma unroll
    for (int j = 0; j < 8; ++j) {
        a0[j] = (__bf16)((x0[j] - mn) * rs * gv0[j] + bv0[j]);
        a1[j] = (__bf16)((x1[j] - mn) * rs * gv1[j] + bv1[j]);
    }
}

// ---------------- weight pack: transpose + bf16 ----------------
__global__ __launch_bounds__(256)
void pack_weights(const float* __restrict__ wq, const float* __restrict__ wk,
                  const float* __restrict__ wv, const float* __restrict__ wo,
                  const float* __restrict__ w1, const float* __restrict__ w2,
                  const float* __restrict__ ow1, __bf16* __restrict__ pk)
{
    int idx = blockIdx.x * 256 + threadIdx.x;
    if (idx >= PK_TOTAL) return;
    float v;
    if (idx < PK_OW1T) {
        int l = idx / PK_LAYER, r = idx - l * PK_LAYER;
        const float* src; int sh, N, off;
        if (r < PK_WKT)      { src = wq + l * 4096;  sh = 6; N = 64;  off = r; }
        else if (r < PK_WVT) { src = wk + l * 4096;  sh = 6; N = 64;  off = r - PK_WKT; }
        else if (r < PK_WOT) { src = wv + l * 4096;  sh = 6; N = 64;  off = r - PK_WVT; }
        else if (r < PK_W1T) { src = wo + l * 4096;  sh = 6; N = 64;  off = r - PK_WOT; }
        else if (r < PK_W2T) { src = w1 + l * 16384; sh = 6; N = 256; off = r - PK_W1T; }
        else                 { src = w2 + l * 16384; sh = 8; N = 64;  off = r - PK_W2T; }
        int col = off >> sh, k = off & ((1 << sh) - 1);
        v = src[k * N + col];
    } else {
        int off = idx - PK_OW1T;
        int col = off / 2496, k = off - col * 2496;
        v = ow1[k * 256 + col];
    }
    pk[idx] = (__bf16)v;
}

__global__ __launch_bounds__(256, 3)
void hstu_layers(const int* __restrict__ dfeat, const int* __restrict__ sfeat,
                 const float* __restrict__ demb, const float* __restrict__ semb,
                 const float* __restrict__ bq, const float* __restrict__ bk,
                 const float* __restrict__ bv, const float* __restrict__ bo,
                 const float* __restrict__ ln1g, const float* __restrict__ ln1b,
                 const float* __restrict__ ln2g, const float* __restrict__ ln2b,
                 const float* __restrict__ b1, const float* __restrict__ b2,
                 const __bf16* __restrict__ pk, __bf16* __restrict__ flatX)
{
    __shared__ __bf16 xb[ROWS * XST];        // 18432 B, residual stream
    __shared__ float qkv[3 * ROWS * QST];    // 30720 B, Q/K/V quarter buffers
                                             // total 49152 B -> 3 blocks/CU

    float* qbuf = qkv;
    float* kbuf = qkv + ROWS * QST;
    float* vbuf = qkv + 2 * ROWS * QST;

    const int tid = threadIdx.x;
    const int lane = tid & 63, wave = tid >> 6;
    const int g = lane >> 4, r16 = lane & 15;
    const int s0 = blockIdx.x * SBLK;

    // ---------------- embedding gather ----------------
    for (int row = wave; row < ROWS; row += 4) {
        int sm = row / 40, f = row % 40;
        float val = 0.0f;
        if (row < SROWS && f < NFEAT && s0 + sm < NSAMP) {
            if (f < NDENSE) {
                int idx = dfeat[(s0 + sm) * NDENSE + f];
                val = demb[(f * VDN + idx) * EDIM + lane];
            } else {
                int idx = sfeat[(s0 + sm) * NSPARSE + (f - NDENSE)];
                val = semb[((long)(f - NDENSE) * VSN + idx) * EDIM + lane];
            }
        }
        xb[row * XST + lane] = (__bf16)val;
    }
    __syncthreads();

    for (int lay = 0; lay < NLAYER; ++lay) {
        const __bf16* wqT = pk + lay * PK_LAYER;
        const __bf16* wkT = wqT + PK_WKT;
        const __bf16* wvT = wqT + PK_WVT;
        const __bf16* woT = wqT + PK_WOT;
        const __bf16* w1T = wqT + PK_W1T;
        const __bf16* w2T = wqT + PK_W2T;
        const float* bq_l = bq + lay * EDIM;
        const float* bk_l = bk + lay * EDIM;
        const float* bv_l = bv + lay * EDIM;
        const float* bo_l = bo + lay * EDIM;
        const float* g1_l = ln1g + lay * EDIM;
        const float* be1_l = ln1b + lay * EDIM;
        const float* g2_l = ln2g + lay * EDIM;
        const float* be2_l = ln2b + lay * EDIM;
        const float* b1_l = b1 + lay * FFDIM;
        const float* b2_l = b2 + lay * EDIM;

        // LN1 fragments for this wave's 2 m-tiles, computed ONCE per layer
        // (statically indexed; reused across all 4 quarters)
        bf16x8 lnA[2][2];
        #pragma unroll
        for (int i = 0; i < 2; ++i) {
            int mt = wave + i * 4;
            ln_frag(&xb[(mt * 16 + r16) * XST], g1_l, be1_l, g, lnA[i][0], lnA[i][1]);
        }

        // O-proj accumulators: this wave owns col strip n_o, all m-tiles.
        const int n_o = wave & 3;
        f32x4 acc_o[MTILES];
        {
            float bz = bo_l[n_o * 16 + r16];
            #pragma unroll
            for (int i = 0; i < MTILES; ++i) { f32x4 t = {bz, bz, bz, bz}; acc_o[i] = t; }
        }

        for (int qt = 0; qt < 4; ++qt) {   // quarter = 16 proj cols = 2 heads
            const int colq = qt * 16 + r16;

            // ---- A1: QKV projection for this quarter (MFMA, K=64) ----
            bf16x8 bfq0 = ldfrag(wqT, EDIM, colq, g * 8);
            bf16x8 bfq1 = ldfrag(wqT, EDIM, colq, 32 + g * 8);
            bf16x8 bfk0 = ldfrag(wkT, EDIM, colq, g * 8);
            bf16x8 bfk1 = ldfrag(wkT, EDIM, colq, 32 + g * 8);
            bf16x8 bfv0 = ldfrag(wvT, EDIM, colq, g * 8);
            bf16x8 bfv1 = ldfrag(wvT, EDIM, colq, 32 + g * 8);
            float biq = bq_l[colq], bik = bk_l[colq], biv = bv_l[colq];

            #pragma unroll
            for (int i = 0; i < 2; ++i) {
                int mt = wave + i * 4;
                f32x4 aq = {biq, biq, biq, biq};
                f32x4 ak = {bik, bik, bik, bik};
                f32x4 av = {biv, biv, biv, biv};
                aq = mfma16(lnA[i][0], bfq0, aq); aq = mfma16(lnA[i][1], bfq1, aq);
                ak = mfma16(lnA[i][0], bfk0, ak); ak = mfma16(lnA[i][1], bfk1, ak);
                av = mfma16(lnA[i][0], bfv0, av); av = mfma16(lnA[i][1], bfv1, av);
                #pragma unroll
                for (int r = 0; r < 4; ++r) {
                    int row = mt * 16 + g * 4 + r;
                    qbuf[row * QST + r16] = aq[r] * QSCL;   // pre-scaled for sigmoid
                    kbuf[row * QST + r16] = ak[r];
                    vbuf[row * QST + r16] = av[r];
                }
            }
            __syncthreads();

            // ---- A2: sigmoid attention, VALU, lane = q row ----
            for (int u = wave; u < SBLK * 2; u += 4) {
                int sm = u >> 1, d0 = (u & 1) * 8;
                int qq = lane < NFEAT ? lane : (NFEAT - 1);
                const float* Qr = &qbuf[(sm * 40 + qq) * QST + d0];
                f32x4 qv0 = *(const f32x4*)Qr;
                f32x4 qv1 = *(const f32x4*)(Qr + 4);
                f32x4 o0 = {0.f, 0.f, 0.f, 0.f}, o1 = {0.f, 0.f, 0.f, 0.f};
                for (int k = 0; k < NFEAT; ++k) {
                    const float* Kr = &kbuf[(sm * 40 + k) * QST + d0];   // broadcast
                    const float* Vr = &vbuf[(sm * 40 + k) * QST + d0];   // broadcast
                    f32x4 kv0 = *(const f32x4*)Kr, kv1 = *(const f32x4*)(Kr + 4);
                    f32x4 vv0 = *(const f32x4*)Vr, vv1 = *(const f32x4*)(Vr + 4);
                    float dot = qv0[0]*kv0[0] + qv0[1]*kv0[1] + qv0[2]*kv0[2] + qv0[3]*kv0[3]
                              + qv1[0]*kv1[0] + qv1[1]*kv1[1] + qv1[2]*kv1[2] + qv1[3]*kv1[3];
                    float sg = sigmoid2(dot);
                    o0 += vv0 * sg;
                    o1 += vv1 * sg;
                }
                if (lane < NFEAT) {      // o overwrites Q in place
                    float* Or = &qbuf[(sm * 40 + lane) * QST + d0];
                    *(f32x4*)Or = o0;
                    *(f32x4*)(Or + 4) = o1;
                }
            }
            __syncthreads();

            // ---- A3: O-proj partial for this quarter (K=16 zero-padded to 32) ----
            bf16x8 bfo;
            if (g < 2) {
                bfo = ldfrag(woT, EDIM, n_o * 16 + r16, qt * 16 + g * 8);
            } else {
                #pragma unroll
                for (int j = 0; j < 8; ++j) bfo[j] = (__bf16)0.0f;
            }
            #pragma unroll
            for (int mt = 0; mt < MTILES; ++mt) {
                bf16x8 af;
                if (g < 2) {
                    const float* orow = &qbuf[(mt * 16 + r16) * QST + g * 8];
                    f32x4 q0 = *(const f32x4*)orow;
                    f32x4 q1 = *(const f32x4*)(orow + 4);
                    #pragma unroll
                    for (int j = 0; j < 4; ++j) { af[j] = (__bf16)q0[j]; af[4 + j] = (__bf16)q1[j]; }
                } else {
                    #pragma unroll
                    for (int j = 0; j < 8; ++j) af[j] = (__bf16)0.0f;
                }
                acc_o[mt] = mfma16(af, bfo, acc_o[mt]);
            }
            __syncthreads();   // next quarter overwrites q/k/v buffers
        }

        // ---- A4: residual add of O-projection ----
        #pragma unroll
        for (int mt = 0; mt < MTILES; ++mt) {
            #pragma unroll
            for (int r = 0; r < 4; ++r) {
                int row = mt * 16 + g * 4 + r, col = n_o * 16 + r16;
                xb[row * XST + col] = (__bf16)((float)xb[row * XST + col] + acc_o[mt][r]);
            }
        }
        __syncthreads();

        // ---- B: MLP, two 128-col FF passes through per-wave LDS scratch ----
        __bf16* ffs = ((__bf16*)qkv) + wave * (16 * FST2);   // 4352 B per wave
        #pragma unroll
        for (int i = 0; i < 2; ++i) {
            int mt = wave + i * 4;
            bf16x8 a0, a1;
            ln_frag(&xb[(mt * 16 + r16) * XST], g2_l, be2_l, g, a0, a1);
            f32x4 acc2[4];
            #pragma unroll
            for (int n2 = 0; n2 < 4; ++n2) {
                float bz = b2_l[n2 * 16 + r16];
                f32x4 t = {bz, bz, bz, bz};
                acc2[n2] = t;
            }
            #pragma unroll
            for (int p = 0; p < 2; ++p) {
                #pragma unroll
                for (int n = 0; n < 8; ++n) {
                    int col = (p * 8 + n) * 16 + r16;
                    float bz = b1_l[col];
                    f32x4 acc = {bz, bz, bz, bz};
                    acc = mfma16(a0, ldfrag(w1T, EDIM, col, g * 8), acc);
                    acc = mfma16(a1, ldfrag(w1T, EDIM, col, 32 + g * 8), acc);
                    #pragma unroll
                    for (int r = 0; r < 4; ++r)
                        ffs[(g * 4 + r) * FST2 + n * 16 + r16] = (__bf16)gelu_f(acc[r]);
                }
                #pragma unroll
                for (int n2 = 0; n2 < 4; ++n2) {
                    #pragma unroll
                    for (int kf = 0; kf < 4; ++kf) {
                        bf16x8 af = *(const bf16x8*)&ffs[r16 * FST2 + kf * 32 + g * 8];
                        acc2[n2] = mfma16(af,
                            ldfrag(w2T, FFDIM, n2 * 16 + r16, p * 128 + kf * 32 + g * 8),
                            acc2[n2]);
                    }
                }
            }
            #pragma unroll
            for (int n2 = 0; n2 < 4; ++n2) {
                #pragma unroll
                for (int r = 0; r < 4; ++r) {
                    int row = mt * 16 + g * 4 + r, col = n2 * 16 + r16;
                    xb[row * XST + col] = (__bf16)((float)xb[row * XST + col] + acc2[n2][r]);
                }
            }
        }
        __syncthreads();
    }

    // ---------------- write flat activations (bf16) ----------------
    for (int row = wave; row < ROWS; row += 4) {
        int sm = row / 40, f = row % 40;
        if (row < SROWS && f < NFEAT && s0 + sm < NSAMP)
            flatX[((long)(s0 + sm) * NFEAT + f) * EDIM + lane] = xb[row * XST + lane];
    }
}

#define FFSTH 264
__global__ __launch_bounds__(512)
void final_mlp(const __bf16* __restrict__ flatX, const __bf16* __restrict__ ow1T,
               const float* __restrict__ ob1, const float* __restrict__ ow2,
               const float* __restrict__ ob2, float* __restrict__ out)
{
    __shared__ __bf16 hbuf[32 * FFSTH];   // 16896 B
    const int tid = threadIdx.x, lane = tid & 63, wave = tid >> 6;
    const int g = lane >> 4, r16 = lane & 15;
    const int m = wave & 1;              // m-tile 0/1 (16 samples each)
    const long base = (long)blockIdx.x * 32;
    const long arow = (base + m * 16 + r16) * (long)(NFEAT * EDIM);

    f32x4 acc[4];
    #pragma unroll
    for (int i = 0; i < 4; ++i) {
        int n = (wave >> 1) + i * 4;
        float bz = ob1[n * 16 + r16];
        f32x4 t = {bz, bz, bz, bz};
        acc[i] = t;
    }
    for (int kf = 0; kf < 78; ++kf) {    // K = 2496
        bf16x8 af = *(const bf16x8*)&flatX[arow + kf * 32 + g * 8];
        #pragma unroll
        for (int i = 0; i < 4; ++i) {
            int n = (wave >> 1) + i * 4;
            bf16x8 bfr = ldfrag(ow1T, NFEAT * EDIM, n * 16 + r16, kf * 32 + g * 8);
            acc[i] = mfma16(af, bfr, acc[i]);
        }
    }
    #pragma unroll
    for (int i = 0; i < 4; ++i) {
        int n = (wave >> 1) + i * 4;
        #pragma unroll
        for (int r = 0; r < 4; ++r) {
            float h = acc[i][r];
            hbuf[(m * 16 + g * 4 + r) * FFSTH + n * 16 + r16] = (__bf16)(h > 0.f ? h : 0.f);
        }
    }
    __syncthreads();
    float w2v0 = ow2[lane], w2v1 = ow2[64 + lane], w2v2 = ow2[128 + lane], w2v3 = ow2[192 + lane];
    float bias2 = ob2[0];
    #pragma unroll
    for (int i = 0; i < 4; ++i) {
        int sm = wave * 4 + i;
        float part = (float)hbuf[sm * FFSTH + lane]       * w2v0
                   + (float)hbuf[sm * FFSTH + 64 + lane]  * w2v1
                   + (float)hbuf[sm * FFSTH + 128 + lane] * w2v2
                   + (float)hbuf[sm * FFSTH + 192 + lane] * w2v3;
        #pragma unroll
        for (int off = 32; off >= 1; off >>= 1) part += __shfl_xor(part, off);
        if (lane == 0) {
            float z = part + bias2;
            out[base + sm] = __builtin_amdgcn_rcpf(1.0f + __expf(-z));
        }
    }
}

extern "C" void kernel_launch(void* const* d_in, const int* in_sizes, int n_in,
                              void* d_out, int out_size, void* d_ws, size_t ws_size,
                              hipStream_t stream)
{
    const int*   dfeat = (const int*)d_in[0];
    const int*   sfeat = (const int*)d_in[1];
    const float* demb  = (const float*)d_in[2];
    const float* semb  = (const float*)d_in[3];
    const float* wq    = (const float*)d_in[4];
    const float* bq    = (const float*)d_in[5];
    const float* wk    = (const float*)d_in[6];
    const float* bk    = (const float*)d_in[7];
    const float* wv    = (const float*)d_in[8];
    const float* bv    = (const float*)d_in[9];
    const float* wo    = (const float*)d_in[10];
    const float* bo    = (const float*)d_in[11];
    const float* ln1g  = (const float*)d_in[12];
    const float* ln1b  = (const float*)d_in[13];
    const float* ln2g  = (const float*)d_in[14];
    const float* ln2b  = (const float*)d_in[15];
    const float* w1    = (const float*)d_in[16];
    const float* b1    = (const float*)d_in[17];
    const float* w2    = (const float*)d_in[18];
    const float* b2    = (const float*)d_in[19];
    const float* ow1   = (const float*)d_in[20];
    const float* ob1   = (const float*)d_in[21];
    const float* ow2   = (const float*)d_in[22];
    const float* ob2   = (const float*)d_in[23];

    __bf16* flatX = (__bf16*)d_ws;                 // 40.9 MB
    __bf16* pk    = ((__bf16*)d_ws) + FLATX_ELEMS; // +1.7 MB packed weights
    float* out = (float*)d_out;

    pack_weights<<<(PK_TOTAL + 255) / 256, 256, 0, stream>>>(wq, wk, wv, wo, w1, w2, ow1, pk);
    hstu_layers<<<(NSAMP + SBLK - 1) / SBLK, 256, 0, stream>>>(dfeat, sfeat, demb, semb,
        bq, bk, bv, bo, ln1g, ln1b, ln2g, ln2b, b1, b2, pk, flatX);
    final_mlp<<<NSAMP / 32, 512, 0, stream>>>(flatX, pk + PK_OW1T, ob1, ow2, ob2, out);
}